// Round 9
// baseline (4789.528 us; speedup 1.0000x reference)
//
#include <hip/hip_runtime.h>

// ---------------------------------------------------------------------------
// dLSTM R9: clean streaming, zero VGPR-weight arrays.
// R4-R8 lesson: the compiler cannot be forced (from HIP) to hold 128 weight
// VGPRs/wave — it spills/remats, and the resulting scratch/HBM re-reads gave
// the invariant 13.6-16us/phase. R9 stops fighting: weights have NO VGPR
// arrays. 96 KB/CU (12 chunks/wave = phase-A tile0 k=0..11) live in LDS,
// loaded once; the rest (~106 MB/step chip-wide) streams via global_load_lds
// through a 6-slot/wave LDS ring with a hand-derived counted-vmcnt schedule.
// A-operands are plain loads (L2-served; R4 fence barrier keeps them fresh
// at ~2MB/phase first-touch). h/out/c plain stores. Epilogue red[] aliases
// the ring region (dead by then; resync'd).
// ---------------------------------------------------------------------------

typedef __attribute__((ext_vector_type(8))) short short8;
typedef __attribute__((ext_vector_type(4))) short short4v;
typedef __attribute__((ext_vector_type(4))) float f32x4;

#define MFMA16(a, b, c) __builtin_amdgcn_mfma_f32_16x16x32_bf16((a), (b), (c), 0, 0, 0)
#define GDMA(gp, lp)                                                        \
  __builtin_amdgcn_global_load_lds(                                         \
      (const __attribute__((address_space(1))) unsigned int*)(gp),          \
      (__attribute__((address_space(3))) unsigned int*)(lp), 16, 0, 0)

static constexpr int BATCH = 32;
static constexpr int HID = 2048;
static constexpr int NWG = 256;
static constexpr int NTHR = 512;           // 8 waves
static constexpr int BH = BATCH * HID;     // 65536
static constexpr size_t WMAT = (size_t)8192 * 2048;
// LDS: [0,48K) rings 6KB/wave (red 16KB aliases [0,16K) in epilogue)
//      [48K,144K) resident weights 12KB/wave
static constexpr int LDS_RES = 49152;
static constexpr int LDS_BYTES = 147456;

#define AT_ADD(p, v) __hip_atomic_fetch_add((p), (v), __ATOMIC_RELAXED, __HIP_MEMORY_SCOPE_AGENT)
#define AT_LD(p) __hip_atomic_load((p), __ATOMIC_RELAXED, __HIP_MEMORY_SCOPE_AGENT)
#define AT_ST(p, v) __hip_atomic_store((p), (v), __ATOMIC_RELAXED, __HIP_MEMORY_SCOPE_AGENT)

__device__ __forceinline__ unsigned short f2bf(float x) {
  unsigned u = __float_as_uint(x);
  u += 0x7FFFu + ((u >> 16) & 1u);
  return (unsigned short)(u >> 16);
}
__device__ __forceinline__ float sigm(float x) { return 1.f / (1.f + __expf(-x)); }
__device__ __forceinline__ float tanh_(float x) {
  float e = __expf(2.f * x);
  return 1.f - 2.f / (e + 1.f);
}

__global__ void cvt_bf16_k(const float* __restrict__ s, unsigned short* __restrict__ d,
                           long n4) {
  long i = blockIdx.x * (long)blockDim.x + threadIdx.x;
  long st = (long)gridDim.x * blockDim.x;
  for (; i < n4; i += st) {
    float4 v = ((const float4*)s)[i];
    short4v o;
    o.x = (short)f2bf(v.x); o.y = (short)f2bf(v.y);
    o.z = (short)f2bf(v.z); o.w = (short)f2bf(v.w);
    ((short4v*)d)[i] = o;
  }
}

// Wout f32 [2048][2048] -> WoutT bf16 transposed
__global__ void tcvt_k(const float* __restrict__ src, unsigned short* __restrict__ dst) {
  __shared__ float T[64][65];
  const int jb = blockIdx.x * 64, kb = blockIdx.y * 64;
  const int tid = threadIdx.x;
#pragma unroll
  for (int r = 0; r < 4; ++r) {
    const int row = r * 16 + (tid >> 4), c4 = (tid & 15) * 4;
    float4 v = *(const float4*)&src[(size_t)(jb + row) * 2048 + kb + c4];
    T[row][c4] = v.x; T[row][c4 + 1] = v.y; T[row][c4 + 2] = v.z; T[row][c4 + 3] = v.w;
  }
  __syncthreads();
#pragma unroll
  for (int r = 0; r < 4; ++r) {
    const int k = r * 16 + (tid >> 4), j4 = (tid & 15) * 4;
    short4v o;
    o.x = (short)f2bf(T[j4][k]);     o.y = (short)f2bf(T[j4 + 1][k]);
    o.z = (short)f2bf(T[j4 + 2][k]); o.w = (short)f2bf(T[j4 + 3][k]);
    *(short4v*)&dst[(size_t)(kb + k) * 2048 + jb + j4] = o;
  }
}

// Wfp(packed) = A[8192x2048] . Bt[2048x2048]^T ; grid(64,16), 4 waves (2x2)
__global__ void gemm_pack_k(const unsigned short* __restrict__ A,
                            const unsigned short* __restrict__ Bt,
                            unsigned short* __restrict__ Wfp) {
  __shared__ __align__(16) unsigned short As[128][72], Bs[128][72];
  const int tid = threadIdx.x, wv = tid >> 6, lane = tid & 63;
  const int wm = wv >> 1, wn = wv & 1;
  const int g0 = blockIdx.x * 128, k0 = blockIdx.y * 128;
  f32x4 acc[4][4];
#pragma unroll
  for (int i = 0; i < 4; ++i)
#pragma unroll
    for (int j = 0; j < 4; ++j) acc[i][j] = (f32x4){0.f, 0.f, 0.f, 0.f};

  for (int kt = 0; kt < 32; ++kt) {
#pragma unroll
    for (int rr = 0; rr < 4; ++rr) {
      const int row = rr * 32 + (tid >> 3), c8 = (tid & 7) * 8;
      *(short8*)&As[row][c8] = *(const short8*)&A[(size_t)(g0 + row) * 2048 + kt * 64 + c8];
      *(short8*)&Bs[row][c8] = *(const short8*)&Bt[(size_t)(k0 + row) * 2048 + kt * 64 + c8];
    }
    __syncthreads();
#pragma unroll
    for (int kk = 0; kk < 2; ++kk) {
      short8 af[4], bf[4];
#pragma unroll
      for (int mi = 0; mi < 4; ++mi)
        af[mi] = *(const short8*)&As[wm * 64 + mi * 16 + (lane & 15)][kk * 32 + (lane >> 4) * 8];
#pragma unroll
      for (int ni = 0; ni < 4; ++ni)
        bf[ni] = *(const short8*)&Bs[wn * 64 + ni * 16 + (lane & 15)][kk * 32 + (lane >> 4) * 8];
#pragma unroll
      for (int mi = 0; mi < 4; ++mi)
#pragma unroll
        for (int ni = 0; ni < 4; ++ni)
          acc[mi][ni] = MFMA16(af[mi], bf[ni], acc[mi][ni]);
    }
    __syncthreads();
  }
#pragma unroll
  for (int mi = 0; mi < 4; ++mi)
#pragma unroll
    for (int ni = 0; ni < 4; ++ni)
#pragma unroll
      for (int r = 0; r < 4; ++r) {
        const int g = g0 + wm * 64 + mi * 16 + (lane >> 4) * 4 + r;
        const int k = k0 + wn * 64 + ni * 16 + (lane & 15);
        const int gateblk = g >> 11, gcol = g & 2047;
        const int wgp = gcol >> 3, nn = (gcol & 7) + 8 * (gateblk & 1), tile = gateblk >> 1;
        const int kblk = k >> 5, e = k & 7, lane_p = nn + 16 * ((k >> 3) & 3);
        Wfp[(((size_t)(wgp * 2 + tile) * 64 + kblk) * 64 + lane_p) * 8 + e] =
            f2bf(acc[mi][ni][r]);
      }
}

__global__ void pack_W1_k(const float* __restrict__ src, unsigned short* __restrict__ dst) {
  const int bid = blockIdx.x;              // 512: [wg(256)][tile(2)]
  const int wg = bid >> 1, tile = bid & 1;
  const int tid = threadIdx.x;
  __shared__ __align__(16) unsigned short L[16][2056];
  for (int i = tid; i < 16 * 512; i += 256) {
    const int r = i >> 9, c4 = i & 511;
    const int gr = tile * 4096 + (r < 8 ? wg * 8 + r : 2048 + wg * 8 + r - 8);
    float4 v = ((const float4*)(src + (size_t)gr * 2048))[c4];
    short4v o;
    o.x = (short)f2bf(v.x); o.y = (short)f2bf(v.y);
    o.z = (short)f2bf(v.z); o.w = (short)f2bf(v.w);
    *(short4v*)&L[r][c4 * 4] = o;
  }
  __syncthreads();
  short8* dchunks = (short8*)dst;
  const size_t cbase = (size_t)(wg * 2 + tile) * 64;
  for (int c = tid; c < 4096; c += 256) {
    const int lane = c & 63, kblk = c >> 6;
    const int nn = lane & 15, kb = (lane >> 4) << 3;
    short8 v = *(const short8*)&L[nn][kblk * 32 + kb];
    dchunks[(cbase + kblk) * 64 + lane] = v;
  }
}

__global__ void bias_k(const float* __restrict__ Wih, const float* __restrict__ bout,
                       const float* __restrict__ bih, const float* __restrict__ bhh,
                       float* bA0, float* bAf, float* bB) {
  const int g = blockIdx.x * 8 + (threadIdx.x >> 6);
  const int lane = threadIdx.x & 63;
  float s = 0.f;
  for (int i = 0; i < 32; ++i)
    s += Wih[(size_t)g * 2048 + i * 64 + lane] * bout[i * 64 + lane];
  for (int off = 32; off; off >>= 1) s += __shfl_down(s, off);
  if (lane == 0) {
    const float b0 = bih[g] + bhh[g];
    bA0[g] = b0; bAf[g] = b0 + s;
    bB[g] = bih[8192 + g] + bhh[8192 + g];
  }
}

__global__ void init_k(const float* __restrict__ h0, const float* __restrict__ c0,
                       unsigned short* h0p, unsigned short* h1p, unsigned short* zbuf,
                       float* c0f, float* c1f, unsigned* bar) {
  int i = blockIdx.x * blockDim.x + threadIdx.x;
  if (i < BH) {
    const int e = i & 7, lane = (i >> 3) & 63, kblk = (i >> 9) & 63, mtile = i >> 15;
    const int m = mtile * 16 + (lane & 15);
    const int k = kblk * 32 + ((lane >> 4) << 3) + e;
    h0p[i] = f2bf(h0[m * HID + k]);
    h1p[i] = f2bf(h0[BH + m * HID + k]);
    zbuf[i] = 0;
    c0f[i] = c0[i];
    c1f[i] = c0[BH + i];
  }
  if (i < 320) bar[i] = 0u;
}

// R4-proven hierarchical fence barrier (8 groups of 32 -> master -> epoch)
__device__ __forceinline__ void grid_barrier(unsigned* bar, int bno) {
  asm volatile("s_waitcnt vmcnt(0)" ::: "memory");
  __syncthreads();
  if (threadIdx.x == 0) {
    __builtin_amdgcn_fence(__ATOMIC_RELEASE, "agent");
    const int g = blockIdx.x >> 5;
    unsigned a = AT_ADD(&bar[g * 32], 1u);
    if (a == (unsigned)(32 * bno - 1)) {
      unsigned m = AT_ADD(&bar[256], 1u);
      if (m == (unsigned)(8 * bno - 1)) AT_ST(&bar[288], (unsigned)bno);
    }
    while (AT_LD(&bar[288]) < (unsigned)bno) __builtin_amdgcn_s_sleep(2);
    __builtin_amdgcn_fence(__ATOMIC_ACQUIRE, "agent");
  }
  __syncthreads();
}

// shared epilogue: red[] (aliases ring LDS, guarded by syncs) -> gates -> cell
#define EPILOG(CBUF, HOUTP, OUTP, BSEL)                                           \
  __syncthreads();                                                                \
  *(f32x4*)&red[((w * 2 + 0) * 64 + lane) * 4] = acc00;                           \
  *(f32x4*)&red[((w * 2 + 1) * 64 + lane) * 4] = acc01;                           \
  __syncthreads();                                                                \
  float gi = 0.f, gf_ = 0.f;                                                      \
  if (tid < 256) {                                                                \
    const int b = tid >> 3, cc = tid & 7, m = b >> 4, br = b & 15;                \
    const int reg = br & 3, lb = (br >> 2) << 4;                                  \
    _Pragma("unroll")                                                             \
    for (int ww = 0; ww < 8; ++ww) {                                              \
      gi  += red[((ww * 2 + m) * 64 + lb + cc) * 4 + reg];                        \
      gf_ += red[((ww * 2 + m) * 64 + lb + cc + 8) * 4 + reg];                    \
    }                                                                             \
  }                                                                               \
  __syncthreads();                                                                \
  *(f32x4*)&red[((w * 2 + 0) * 64 + lane) * 4] = acc10;                           \
  *(f32x4*)&red[((w * 2 + 1) * 64 + lane) * 4] = acc11;                           \
  __syncthreads();                                                                \
  if (tid < 256) {                                                                \
    const int b = tid >> 3, cc = tid & 7, m = b >> 4, br = b & 15;                \
    const int reg = br & 3, lb = (br >> 2) << 4;                                  \
    float gg = 0.f, go = 0.f;                                                     \
    _Pragma("unroll")                                                             \
    for (int ww = 0; ww < 8; ++ww) {                                              \
      gg += red[((ww * 2 + m) * 64 + lb + cc) * 4 + reg];                         \
      go += red[((ww * 2 + m) * 64 + lb + cc + 8) * 4 + reg];                     \
    }                                                                             \
    const int col = wg * 8 + cc;                                                  \
    gi  += (BSEL)[col];                                                           \
    gf_ += (BSEL)[2048 + col];                                                    \
    gg  += (BSEL)[4096 + col];                                                    \
    go  += (BSEL)[6144 + col];                                                    \
    const float iv = sigm(gi), fv = sigm(gf_), gv = tanh_(gg), ov = sigm(go);     \
    const float cold = (CBUF)[b * HID + col];                                     \
    const float cnew = fv * cold + iv * gv;                                       \
    const float hnew = ov * tanh_(cnew);                                          \
    (CBUF)[b * HID + col] = cnew;                                                 \
    const int kblk = col >> 5, lh = (col >> 3) & 3, e = col & 7;                  \
    const int lane_p = (b & 15) | (lh << 4), mt = b >> 4;                         \
    (HOUTP)[((size_t)(mt * 64 + kblk) * 64 + lane_p) * 8 + e] = f2bf(hnew);       \
    if (OUTP) ((float*)(OUTP))[b * HID + col] = hnew;                             \
  }

// Phase A stream: 20 items; i<12 -> tile1(k=i); i>=12 -> pairs (tile0,tile1)
// for k=12..15. Schedule (derived item-by-item): prologue 6; wait vmcnt:
// k<12:5, k=12,13:4, k=14:2, k=15:0. Issue: k<=11 -> item k+6; k==12 -> 18,19.
#define A_IT(i)                                                                   \
  ((i) < 12 ? (WAt1 + (size_t)(i) * 1024)                                         \
            : ((((i) - 12) & 1) ? (WAt1 + (size_t)(12 + (((i) - 12) >> 1)) * 1024)\
                                : (WAt0 + (size_t)(12 + (((i) - 12) >> 1)) * 1024)))

#define PHASE_A(CBUF, HOUTP, OUTP, BSEL)                                          \
  {                                                                               \
    const short8* pA0 = (const short8*)Asrc + (s * 16) * 64 + lane;               \
    const short8* pA1 = pA0 + 64 * 64;                                            \
    _Pragma("unroll")                                                             \
    for (int i = 0; i < 6; ++i) GDMA(A_IT(i), lds3 + ring + (i % 6) * 1024);      \
    f32x4 acc00 = {0.f, 0.f, 0.f, 0.f}, acc01 = acc00, acc10 = acc00, acc11 = acc00; \
    _Pragma("unroll")                                                             \
    for (int k = 0; k < 16; ++k) {                                                \
      if (k < 12)       { asm volatile("s_waitcnt vmcnt(5)" ::: "memory"); }      \
      else if (k <= 13) { asm volatile("s_waitcnt vmcnt(4)" ::: "memory"); }      \
      else if (k == 14) { asm volatile("s_waitcnt vmcnt(2)" ::: "memory"); }      \
      else              { asm volatile("s_waitcnt vmcnt(0)" ::: "memory"); }      \
      __builtin_amdgcn_sched_barrier(0);                                          \
      short8 b0 = (k < 12)                                                        \
          ? *(const short8*)(smem + res + k * 1024 + lane * 16)                   \
          : *(const short8*)(smem + ring + ((12 + 2 * (k - 12)) % 6) * 1024 + lane * 16); \
      short8 b1 = (k < 12)                                                        \
          ? *(const short8*)(smem + ring + (k % 6) * 1024 + lane * 16)            \
          : *(const short8*)(smem + ring + ((13 + 2 * (k - 12)) % 6) * 1024 + lane * 16); \
      short8 a0 = pA0[k * 64];                                                    \
      short8 a1 = pA1[k * 64];                                                    \
      acc00 = MFMA16(a0, b0, acc00); acc01 = MFMA16(a1, b0, acc01);               \
      acc10 = MFMA16(a0, b1, acc10); acc11 = MFMA16(a1, b1, acc11);               \
      if (k <= 11) { GDMA(A_IT(k + 6), lds3 + ring + ((k + 6) % 6) * 1024); }     \
      if (k == 12) {                                                              \
        GDMA(A_IT(18), lds3 + ring + 0 * 1024);                                   \
        GDMA(A_IT(19), lds3 + ring + 1 * 1024);                                   \
      }                                                                           \
    }                                                                             \
    EPILOG(CBUF, HOUTP, OUTP, BSEL)                                               \
  }

// Phase B stream: 32 items, pairs (tile0,tile1) per k. prologue 6;
// wait: k<=13:4, k=14:2, k=15:0; issue 2 items (2k+6,2k+7) for k<=12.
#define B_IT(i)                                                                   \
  (((i) & 1) ? (WBt1 + (size_t)((i) >> 1) * 1024) : (WBt0 + (size_t)((i) >> 1) * 1024))

#define PHASE_B(CBUF, HOUTP, OUTP, BSEL)                                          \
  {                                                                               \
    const short8* pA0 = (const short8*)Asrc + (s * 16) * 64 + lane;               \
    const short8* pA1 = pA0 + 64 * 64;                                            \
    _Pragma("unroll")                                                             \
    for (int i = 0; i < 6; ++i) GDMA(B_IT(i), lds3 + ring + (i % 6) * 1024);      \
    f32x4 acc00 = {0.f, 0.f, 0.f, 0.f}, acc01 = acc00, acc10 = acc00, acc11 = acc00; \
    _Pragma("unroll")                                                             \
    for (int k = 0; k < 16; ++k) {                                                \
      if (k <= 13)      { asm volatile("s_waitcnt vmcnt(4)" ::: "memory"); }      \
      else if (k == 14) { asm volatile("s_waitcnt vmcnt(2)" ::: "memory"); }      \
      else              { asm volatile("s_waitcnt vmcnt(0)" ::: "memory"); }      \
      __builtin_amdgcn_sched_barrier(0);                                          \
      short8 b0 = *(const short8*)(smem + ring + ((2 * k) % 6) * 1024 + lane * 16);     \
      short8 b1 = *(const short8*)(smem + ring + ((2 * k + 1) % 6) * 1024 + lane * 16); \
      short8 a0 = pA0[k * 64];                                                    \
      short8 a1 = pA1[k * 64];                                                    \
      acc00 = MFMA16(a0, b0, acc00); acc01 = MFMA16(a1, b0, acc01);               \
      acc10 = MFMA16(a0, b1, acc10); acc11 = MFMA16(a1, b1, acc11);               \
      if (k <= 12) {                                                              \
        GDMA(B_IT(2 * k + 6), lds3 + ring + ((2 * k + 6) % 6) * 1024);            \
        GDMA(B_IT(2 * k + 7), lds3 + ring + ((2 * k + 7) % 6) * 1024);            \
      }                                                                           \
    }                                                                             \
    EPILOG(CBUF, HOUTP, OUTP, BSEL)                                               \
  }

__global__ __launch_bounds__(NTHR, 2) void lstm_persist(
    const unsigned short* __restrict__ Wfp, const unsigned short* __restrict__ Wh0p,
    const unsigned short* __restrict__ Wi1p, const unsigned short* __restrict__ Wh1p,
    const float* __restrict__ bA0, const float* __restrict__ bAf,
    const float* __restrict__ bB,
    unsigned short* h0p, unsigned short* h1p, const unsigned short* zbuf,
    float* c0f, float* c1f, float* __restrict__ out, int T, unsigned* bar) {
  extern __shared__ __align__(16) char smem[];
  auto* lds3 = (__attribute__((address_space(3))) char*)smem;
  float* red = (float*)smem;                    // aliases ring region [0,16K)
  const int wg = blockIdx.x, tid = threadIdx.x;
  const int w = tid >> 6, lane = tid & 63;
  const int p = w >> 2, s = w & 3;
  const int ring = w * 6144;                    // 6 slots x 1KB per wave
  const int res = LDS_RES + w * 12288;          // 12 resident chunks per wave
  const unsigned short* M0 = p ? Wh0p : Wfp;
  const unsigned short* M1 = p ? Wh1p : Wi1p;
  const char* WAt0 = (const char*)M0 + (((size_t)(wg * 2 + 0) * 64) + s * 16) * 1024 + lane * 16;
  const char* WAt1 = (const char*)M0 + (((size_t)(wg * 2 + 1) * 64) + s * 16) * 1024 + lane * 16;
  const char* WBt0 = (const char*)M1 + (((size_t)(wg * 2 + 0) * 64) + s * 16) * 1024 + lane * 16;
  const char* WBt1 = (const char*)M1 + (((size_t)(wg * 2 + 1) * 64) + s * 16) * 1024 + lane * 16;

  // resident prologue: phase-A tile0 chunks k=0..11 -> LDS, once
#pragma unroll
  for (int c = 0; c < 12; ++c) GDMA(WAt0 + (size_t)c * 1024, lds3 + res + c * 1024);
  asm volatile("s_waitcnt vmcnt(0)" ::: "memory");
  __syncthreads();

  int bno = 1;
  for (int t = 0; t < T; ++t) {
    const int par = t & 1;
    {  // phase A: gates0 = Wfused*h1(t-1) + Whh0*h0(t-1) -> h0(t), c0
      const unsigned short* Asrc =
          (p == 0) ? ((t == 0) ? zbuf : h1p + par * BH) : (h0p + par * BH);
      const float* bsel = (t == 0) ? bA0 : bAf;
      PHASE_A(c0f, h0p + (par ^ 1) * BH, (float*)nullptr, bsel)
    }
    grid_barrier(bar, bno++);
    {  // phase B: gates1 = Wih1*h0(t) + Whh1*h1(t-1) -> h1(t), c1, out(t)
      const unsigned short* Asrc = (p == 0) ? (h0p + (par ^ 1) * BH) : (h1p + par * BH);
      PHASE_B(c1f, h1p + (par ^ 1) * BH, out + (size_t)t * BH, bB)
    }
    grid_barrier(bar, bno++);
  }
}

extern "C" void kernel_launch(void* const* d_in, const int* in_sizes, int n_in,
                              void* d_out, int out_size, void* d_ws, size_t ws_size,
                              hipStream_t stream) {
  const float* h0 = (const float*)d_in[0];
  const float* c0 = (const float*)d_in[1];
  const float* Wih = (const float*)d_in[2];
  const float* Whh = (const float*)d_in[3];
  const float* bih = (const float*)d_in[4];
  const float* bhh = (const float*)d_in[5];
  const float* Wout = (const float*)d_in[6];
  const float* bout = (const float*)d_in[7];
  float* out = (float*)d_out;
  const int T = out_size / BH;

  unsigned short* Wfp = (unsigned short*)d_ws;
  unsigned short* Wh0p = Wfp + WMAT;
  unsigned short* Wi1p = Wfp + 2 * WMAT;
  unsigned short* Wh1p = Wfp + 3 * WMAT;
  unsigned short* tmpA = Wi1p;    // alias, dead after gemm_pack_k
  unsigned short* WoutT = Wh1p;   // alias, dead after gemm_pack_k
  unsigned short* S = Wfp + 4 * WMAT;
  unsigned short* h0p = S;                   // 2 x 65536 ping-pong
  unsigned short* h1p = S + 131072;          // 2 x 65536
  unsigned short* zbuf = S + 262144;         // 65536
  float* F = (float*)(S + 327680);
  float* c0f = F;
  float* c1f = F + 65536;
  float* bA0 = F + 131072;
  float* bAf = F + 139264;
  float* bB = F + 147456;
  unsigned* bar = (unsigned*)(F + 155648);   // 320 u32

  cvt_bf16_k<<<2048, 256, 0, stream>>>(Wih, tmpA, (long)(WMAT / 4));
  tcvt_k<<<dim3(32, 32), 256, 0, stream>>>(Wout, WoutT);
  gemm_pack_k<<<dim3(64, 16), 256, 0, stream>>>(tmpA, WoutT, Wfp);
  pack_W1_k<<<512, 256, 0, stream>>>(Whh, Wh0p);
  pack_W1_k<<<512, 256, 0, stream>>>(Wih + WMAT, Wi1p);
  pack_W1_k<<<512, 256, 0, stream>>>(Whh + WMAT, Wh1p);
  bias_k<<<1024, 512, 0, stream>>>(Wih, bout, bih, bhh, bA0, bAf, bB);
  init_k<<<256, 256, 0, stream>>>(h0, c0, h0p, h1p, zbuf, c0f, c1f, bar);

  (void)hipFuncSetAttribute((const void*)lstm_persist,
                            hipFuncAttributeMaxDynamicSharedMemorySize, LDS_BYTES);
  lstm_persist<<<NWG, NTHR, LDS_BYTES, stream>>>(Wfp, Wh0p, Wi1p, Wh1p,
                                                 bA0, bAf, bB,
                                                 h0p, h1p, zbuf, c0f, c1f, out, T, bar);
}

// Round 10
// 3751.228 us; speedup vs baseline: 1.2768x; 1.2768x over previous
//
#include <hip/hip_runtime.h>

// ---------------------------------------------------------------------------
// dLSTM R10: FENCE-FREE phase coherence. R4-R9's invariant 13-18us/phase =
// (weights + 64MB/phase A-replication) streamed via L3/HBM because the
// barrier's agent-acquire fence (`buffer_inv sc1`) invalidates L2 EVERY
// phase. Only h (128KB/phase) actually needs cross-phase coherence:
//   - barriers: pure relaxed atomic counters (no fences)            [R5 proven]
//   - h publish: sc0sc1 stores -> hG staging (coherence point)      [R5 proven]
//   - per-XCD copiers (physical XCC_ID election) hG -> Xh[xcd],
//     plain stores (dirty in local L2) + local counter barrier      [R5 proven]
//   - ONE L1-only `buffer_inv` after local barrier; compute A-loads
//     are plain loads from Xh[xcd] = local-L2 hits
//   - weights: R9's exact GDMA ring schedule (proven correct); L2 now stays
//     warm across phases and the L3 weight set is stable -> ~100% L3 hit.
// c stays wg-local plain; out plain stores.
// ---------------------------------------------------------------------------

typedef __attribute__((ext_vector_type(8))) short short8;
typedef __attribute__((ext_vector_type(4))) short short4v;
typedef __attribute__((ext_vector_type(4))) float f32x4;
typedef __attribute__((ext_vector_type(4))) unsigned int u32x4;

#define MFMA16(a, b, c) __builtin_amdgcn_mfma_f32_16x16x32_bf16((a), (b), (c), 0, 0, 0)
#define GDMA(gp, lp)                                                        \
  __builtin_amdgcn_global_load_lds(                                         \
      (const __attribute__((address_space(1))) unsigned int*)(gp),          \
      (__attribute__((address_space(3))) unsigned int*)(lp), 16, 0, 0)

static constexpr int BATCH = 32;
static constexpr int HID = 2048;
static constexpr int NWG = 256;
static constexpr int NTHR = 512;           // 8 waves
static constexpr int BH = BATCH * HID;     // 65536
static constexpr size_t WMAT = (size_t)8192 * 2048;
// LDS: [0,48K) rings 6KB/wave (red 16KB aliases [0,16K) in epilogue)
//      [48K,144K) resident weights 12KB/wave
static constexpr int LDS_RES = 49152;
static constexpr int LDS_BYTES = 147456;

#define AT_ADD(p, v) __hip_atomic_fetch_add((p), (v), __ATOMIC_RELAXED, __HIP_MEMORY_SCOPE_AGENT)
#define AT_LD(p) __hip_atomic_load((p), __ATOMIC_RELAXED, __HIP_MEMORY_SCOPE_AGENT)
#define AT_ST(p, v) __hip_atomic_store((p), (v), __ATOMIC_RELAXED, __HIP_MEMORY_SCOPE_AGENT)

__device__ __forceinline__ unsigned short f2bf(float x) {
  unsigned u = __float_as_uint(x);
  u += 0x7FFFu + ((u >> 16) & 1u);
  return (unsigned short)(u >> 16);
}
__device__ __forceinline__ float sigm(float x) { return 1.f / (1.f + __expf(-x)); }
__device__ __forceinline__ float tanh_(float x) {
  float e = __expf(2.f * x);
  return 1.f - 2.f / (e + 1.f);
}

__global__ void cvt_bf16_k(const float* __restrict__ s, unsigned short* __restrict__ d,
                           long n4) {
  long i = blockIdx.x * (long)blockDim.x + threadIdx.x;
  long st = (long)gridDim.x * blockDim.x;
  for (; i < n4; i += st) {
    float4 v = ((const float4*)s)[i];
    short4v o;
    o.x = (short)f2bf(v.x); o.y = (short)f2bf(v.y);
    o.z = (short)f2bf(v.z); o.w = (short)f2bf(v.w);
    ((short4v*)d)[i] = o;
  }
}

// Wout f32 [2048][2048] -> WoutT bf16 transposed
__global__ void tcvt_k(const float* __restrict__ src, unsigned short* __restrict__ dst) {
  __shared__ float T[64][65];
  const int jb = blockIdx.x * 64, kb = blockIdx.y * 64;
  const int tid = threadIdx.x;
#pragma unroll
  for (int r = 0; r < 4; ++r) {
    const int row = r * 16 + (tid >> 4), c4 = (tid & 15) * 4;
    float4 v = *(const float4*)&src[(size_t)(jb + row) * 2048 + kb + c4];
    T[row][c4] = v.x; T[row][c4 + 1] = v.y; T[row][c4 + 2] = v.z; T[row][c4 + 3] = v.w;
  }
  __syncthreads();
#pragma unroll
  for (int r = 0; r < 4; ++r) {
    const int k = r * 16 + (tid >> 4), j4 = (tid & 15) * 4;
    short4v o;
    o.x = (short)f2bf(T[j4][k]);     o.y = (short)f2bf(T[j4 + 1][k]);
    o.z = (short)f2bf(T[j4 + 2][k]); o.w = (short)f2bf(T[j4 + 3][k]);
    *(short4v*)&dst[(size_t)(kb + k) * 2048 + jb + j4] = o;
  }
}

// Wfp(packed) = A[8192x2048] . Bt[2048x2048]^T ; grid(64,16), 4 waves (2x2)
__global__ void gemm_pack_k(const unsigned short* __restrict__ A,
                            const unsigned short* __restrict__ Bt,
                            unsigned short* __restrict__ Wfp) {
  __shared__ __align__(16) unsigned short As[128][72], Bs[128][72];
  const int tid = threadIdx.x, wv = tid >> 6, lane = tid & 63;
  const int wm = wv >> 1, wn = wv & 1;
  const int g0 = blockIdx.x * 128, k0 = blockIdx.y * 128;
  f32x4 acc[4][4];
#pragma unroll
  for (int i = 0; i < 4; ++i)
#pragma unroll
    for (int j = 0; j < 4; ++j) acc[i][j] = (f32x4){0.f, 0.f, 0.f, 0.f};

  for (int kt = 0; kt < 32; ++kt) {
#pragma unroll
    for (int rr = 0; rr < 4; ++rr) {
      const int row = rr * 32 + (tid >> 3), c8 = (tid & 7) * 8;
      *(short8*)&As[row][c8] = *(const short8*)&A[(size_t)(g0 + row) * 2048 + kt * 64 + c8];
      *(short8*)&Bs[row][c8] = *(const short8*)&Bt[(size_t)(k0 + row) * 2048 + kt * 64 + c8];
    }
    __syncthreads();
#pragma unroll
    for (int kk = 0; kk < 2; ++kk) {
      short8 af[4], bf[4];
#pragma unroll
      for (int mi = 0; mi < 4; ++mi)
        af[mi] = *(const short8*)&As[wm * 64 + mi * 16 + (lane & 15)][kk * 32 + (lane >> 4) * 8];
#pragma unroll
      for (int ni = 0; ni < 4; ++ni)
        bf[ni] = *(const short8*)&Bs[wn * 64 + ni * 16 + (lane & 15)][kk * 32 + (lane >> 4) * 8];
#pragma unroll
      for (int mi = 0; mi < 4; ++mi)
#pragma unroll
        for (int ni = 0; ni < 4; ++ni)
          acc[mi][ni] = MFMA16(af[mi], bf[ni], acc[mi][ni]);
    }
    __syncthreads();
  }
#pragma unroll
  for (int mi = 0; mi < 4; ++mi)
#pragma unroll
    for (int ni = 0; ni < 4; ++ni)
#pragma unroll
      for (int r = 0; r < 4; ++r) {
        const int g = g0 + wm * 64 + mi * 16 + (lane >> 4) * 4 + r;
        const int k = k0 + wn * 64 + ni * 16 + (lane & 15);
        const int gateblk = g >> 11, gcol = g & 2047;
        const int wgp = gcol >> 3, nn = (gcol & 7) + 8 * (gateblk & 1), tile = gateblk >> 1;
        const int kblk = k >> 5, e = k & 7, lane_p = nn + 16 * ((k >> 3) & 3);
        Wfp[(((size_t)(wgp * 2 + tile) * 64 + kblk) * 64 + lane_p) * 8 + e] =
            f2bf(acc[mi][ni][r]);
      }
}

__global__ void pack_W1_k(const float* __restrict__ src, unsigned short* __restrict__ dst) {
  const int bid = blockIdx.x;              // 512: [wg(256)][tile(2)]
  const int wg = bid >> 1, tile = bid & 1;
  const int tid = threadIdx.x;
  __shared__ __align__(16) unsigned short L[16][2056];
  for (int i = tid; i < 16 * 512; i += 256) {
    const int r = i >> 9, c4 = i & 511;
    const int gr = tile * 4096 + (r < 8 ? wg * 8 + r : 2048 + wg * 8 + r - 8);
    float4 v = ((const float4*)(src + (size_t)gr * 2048))[c4];
    short4v o;
    o.x = (short)f2bf(v.x); o.y = (short)f2bf(v.y);
    o.z = (short)f2bf(v.z); o.w = (short)f2bf(v.w);
    *(short4v*)&L[r][c4 * 4] = o;
  }
  __syncthreads();
  short8* dchunks = (short8*)dst;
  const size_t cbase = (size_t)(wg * 2 + tile) * 64;
  for (int c = tid; c < 4096; c += 256) {
    const int lane = c & 63, kblk = c >> 6;
    const int nn = lane & 15, kb = (lane >> 4) << 3;
    short8 v = *(const short8*)&L[nn][kblk * 32 + kb];
    dchunks[(cbase + kblk) * 64 + lane] = v;
  }
}

__global__ void bias_k(const float* __restrict__ Wih, const float* __restrict__ bout,
                       const float* __restrict__ bih, const float* __restrict__ bhh,
                       float* bA0, float* bAf, float* bB) {
  const int g = blockIdx.x * 8 + (threadIdx.x >> 6);
  const int lane = threadIdx.x & 63;
  float s = 0.f;
  for (int i = 0; i < 32; ++i)
    s += Wih[(size_t)g * 2048 + i * 64 + lane] * bout[i * 64 + lane];
  for (int off = 32; off; off >>= 1) s += __shfl_down(s, off);
  if (lane == 0) {
    const float b0 = bih[g] + bhh[g];
    bA0[g] = b0; bAf[g] = b0 + s;
    bB[g] = bih[8192 + g] + bhh[8192 + g];
  }
}

// init: Xh[8 xcds][2 matrices] = initial h (packed layout); zbuf; c; ctl
__global__ void init_k(const float* __restrict__ h0, const float* __restrict__ c0,
                       unsigned short* hX, unsigned short* zbuf,
                       float* c0f, float* c1f, unsigned* ctl) {
  int i = blockIdx.x * blockDim.x + threadIdx.x;
  if (i < BH) {
    const int e = i & 7, lane = (i >> 3) & 63, kblk = (i >> 9) & 63, mtile = i >> 15;
    const int m = mtile * 16 + (lane & 15);
    const int k = kblk * 32 + ((lane >> 4) << 3) + e;
    const unsigned short v0 = f2bf(h0[m * HID + k]);
    const unsigned short v1 = f2bf(h0[BH + m * HID + k]);
#pragma unroll
    for (int x = 0; x < 8; ++x) {
      hX[(size_t)x * 131072 + i] = v0;
      hX[(size_t)x * 131072 + 65536 + i] = v1;
    }
    zbuf[i] = 0;
    c0f[i] = c0[i];
    c1f[i] = c0[BH + i];
  }
  if (i < 832) ctl[i] = 0u;
}

// ---------------- phase sync: counter gbar -> copy hG->Xh[xcd] -> lbar ------
// ctl: [g*32] g<8 gbar groups | [256] master | [288] epoch
//      [320+x*32] lbar | [576+x*32] elect
__device__ __forceinline__ void phase_sync(unsigned* ctl, int bno, int lbno, int xcc,
                                           int role, int n_x, int n_c, int w, int lane,
                                           const unsigned short* hGm,
                                           unsigned short* Xm) {
  asm volatile("s_waitcnt vmcnt(0)" ::: "memory");   // h-stores at coherence pt
  __syncthreads();
  if (threadIdx.x == 0) {
    const int g = blockIdx.x >> 5;
    unsigned a = AT_ADD(&ctl[g * 32], 1u);
    if (a == (unsigned)(32 * bno - 1)) {
      unsigned m = AT_ADD(&ctl[256], 1u);
      if (m == (unsigned)(8 * bno - 1)) AT_ST(&ctl[288], (unsigned)bno);
    }
    while (AT_LD(&ctl[288]) < (unsigned)bno) __builtin_amdgcn_s_sleep(1);
  }
  __syncthreads();
  // copiers: hG (sc0sc1 loads: coherence point) -> Xh[xcd] (plain stores ->
  // dirty in OWN XCD's L2; physical co-location by XCC_ID election)
  if (role < n_c) {
    for (int c = role * 8 + w; c < 128; c += n_c * 8) {
      const unsigned short* sp = hGm + c * 512 + lane * 8;
      u32x4 v;
      asm volatile("global_load_dwordx4 %0, %1, off sc0 sc1"
                   : "=v"(v) : "v"((unsigned long long)(size_t)sp) : "memory");
      asm volatile("s_waitcnt vmcnt(0)" ::: "memory");
      *(u32x4*)(Xm + c * 512 + lane * 8) = v;
    }
  }
  asm volatile("s_waitcnt vmcnt(0)" ::: "memory");
  __syncthreads();
  if (threadIdx.x == 0) {
    AT_ADD(&ctl[320 + xcc * 32], 1u);
    while (AT_LD(&ctl[320 + xcc * 32]) < (unsigned)(n_x * lbno))
      __builtin_amdgcn_s_sleep(1);
  }
  __syncthreads();
  asm volatile("buffer_inv" ::: "memory");   // L1-only: fresh view of Xh
}

// shared epilogue: red[] (aliases ring LDS, guarded by syncs) -> gates -> cell
// h published via sc0sc1 store to hG staging (device-coherent, tiny).
#define EPILOG(CBUF, HOUTP, OUTP, BSEL)                                           \
  __syncthreads();                                                                \
  *(f32x4*)&red[((w * 2 + 0) * 64 + lane) * 4] = acc00;                           \
  *(f32x4*)&red[((w * 2 + 1) * 64 + lane) * 4] = acc01;                           \
  __syncthreads();                                                                \
  float gi = 0.f, gf_ = 0.f;                                                      \
  if (tid < 256) {                                                                \
    const int b = tid >> 3, cc = tid & 7, m = b >> 4, br = b & 15;                \
    const int reg = br & 3, lb = (br >> 2) << 4;                                  \
    _Pragma("unroll")                                                             \
    for (int ww = 0; ww < 8; ++ww) {                                              \
      gi  += red[((ww * 2 + m) * 64 + lb + cc) * 4 + reg];                        \
      gf_ += red[((ww * 2 + m) * 64 + lb + cc + 8) * 4 + reg];                    \
    }                                                                             \
  }                                                                               \
  __syncthreads();                                                                \
  *(f32x4*)&red[((w * 2 + 0) * 64 + lane) * 4] = acc10;                           \
  *(f32x4*)&red[((w * 2 + 1) * 64 + lane) * 4] = acc11;                           \
  __syncthreads();                                                                \
  if (tid < 256) {                                                                \
    const int b = tid >> 3, cc = tid & 7, m = b >> 4, br = b & 15;                \
    const int reg = br & 3, lb = (br >> 2) << 4;                                  \
    float gg = 0.f, go = 0.f;                                                     \
    _Pragma("unroll")                                                             \
    for (int ww = 0; ww < 8; ++ww) {                                              \
      gg += red[((ww * 2 + m) * 64 + lb + cc) * 4 + reg];                         \
      go += red[((ww * 2 + m) * 64 + lb + cc + 8) * 4 + reg];                     \
    }                                                                             \
    const int col = wg * 8 + cc;                                                  \
    gi  += (BSEL)[col];                                                           \
    gf_ += (BSEL)[2048 + col];                                                    \
    gg  += (BSEL)[4096 + col];                                                    \
    go  += (BSEL)[6144 + col];                                                    \
    const float iv = sigm(gi), fv = sigm(gf_), gv = tanh_(gg), ov = sigm(go);     \
    const float cold = (CBUF)[b * HID + col];                                     \
    const float cnew = fv * cold + iv * gv;                                       \
    const float hnew = ov * tanh_(cnew);                                          \
    (CBUF)[b * HID + col] = cnew;                                                 \
    const int kblk = col >> 5, lh = (col >> 3) & 3, e = col & 7;                  \
    const int lane_p = (b & 15) | (lh << 4), mt = b >> 4;                         \
    const unsigned hv = (unsigned)f2bf(hnew);                                     \
    unsigned long long ha = (unsigned long long)(size_t)                          \
        ((HOUTP) + ((size_t)(mt * 64 + kblk) * 64 + lane_p) * 8 + e);             \
    asm volatile("global_store_short %0, %1, off sc0 sc1"                         \
                 :: "v"(ha), "v"(hv) : "memory");                                 \
    if (OUTP) ((float*)(OUTP))[b * HID + col] = hnew;                             \
  }

// Phase A stream (R9-proven): 20 items; i<12 -> tile1(k=i); i>=12 -> pairs
// (tile0,tile1) k=12..15. prologue 6; wait vmcnt: k<12:5, k=12,13:4, k=14:2,
// k=15:0. Issue: k<=11 -> item k+6; k==12 -> 18,19.
#define A_IT(i)                                                                   \
  ((i) < 12 ? (WAt1 + (size_t)(i) * 1024)                                         \
            : ((((i) - 12) & 1) ? (WAt1 + (size_t)(12 + (((i) - 12) >> 1)) * 1024)\
                                : (WAt0 + (size_t)(12 + (((i) - 12) >> 1)) * 1024)))

#define PHASE_A(CBUF, HOUTP, OUTP, BSEL)                                          \
  {                                                                               \
    const short8* pA0 = (const short8*)Asrc + (s * 16) * 64 + lane;               \
    const short8* pA1 = pA0 + 64 * 64;                                            \
    _Pragma("unroll")                                                             \
    for (int i = 0; i < 6; ++i) GDMA(A_IT(i), lds3 + ring + (i % 6) * 1024);      \
    f32x4 acc00 = {0.f, 0.f, 0.f, 0.f}, acc01 = acc00, acc10 = acc00, acc11 = acc00; \
    _Pragma("unroll")                                                             \
    for (int k = 0; k < 16; ++k) {                                                \
      if (k < 12)       { asm volatile("s_waitcnt vmcnt(5)" ::: "memory"); }      \
      else if (k <= 13) { asm volatile("s_waitcnt vmcnt(4)" ::: "memory"); }      \
      else if (k == 14) { asm volatile("s_waitcnt vmcnt(2)" ::: "memory"); }      \
      else              { asm volatile("s_waitcnt vmcnt(0)" ::: "memory"); }      \
      __builtin_amdgcn_sched_barrier(0);                                          \
      short8 b0 = (k < 12)                                                        \
          ? *(const short8*)(smem + res + k * 1024 + lane * 16)                   \
          : *(const short8*)(smem + ring + ((12 + 2 * (k - 12)) % 6) * 1024 + lane * 16); \
      short8 b1 = (k < 12)                                                        \
          ? *(const short8*)(smem + ring + (k % 6) * 1024 + lane * 16)            \
          : *(const short8*)(smem + ring + ((13 + 2 * (k - 12)) % 6) * 1024 + lane * 16); \
      short8 a0 = pA0[k * 64];                                                    \
      short8 a1 = pA1[k * 64];                                                    \
      acc00 = MFMA16(a0, b0, acc00); acc01 = MFMA16(a1, b0, acc01);               \
      acc10 = MFMA16(a0, b1, acc10); acc11 = MFMA16(a1, b1, acc11);               \
      if (k <= 11) { GDMA(A_IT(k + 6), lds3 + ring + ((k + 6) % 6) * 1024); }     \
      if (k == 12) {                                                              \
        GDMA(A_IT(18), lds3 + ring + 0 * 1024);                                   \
        GDMA(A_IT(19), lds3 + ring + 1 * 1024);                                   \
      }                                                                           \
    }                                                                             \
    EPILOG(CBUF, HOUTP, OUTP, BSEL)                                               \
  }

// Phase B stream (R9-proven): 32 items, pairs (tile0,tile1) per k. prologue 6;
// wait: k<=13:4, k=14:2, k=15:0; issue 2 items (2k+6,2k+7) for k<=12.
#define B_IT(i)                                                                   \
  (((i) & 1) ? (WBt1 + (size_t)((i) >> 1) * 1024) : (WBt0 + (size_t)((i) >> 1) * 1024))

#define PHASE_B(CBUF, HOUTP, OUTP, BSEL)                                          \
  {                                                                               \
    const short8* pA0 = (const short8*)Asrc + (s * 16) * 64 + lane;               \
    const short8* pA1 = pA0 + 64 * 64;                                            \
    _Pragma("unroll")                                                             \
    for (int i = 0; i < 6; ++i) GDMA(B_IT(i), lds3 + ring + (i % 6) * 1024);      \
    f32x4 acc00 = {0.f, 0.f, 0.f, 0.f}, acc01 = acc00, acc10 = acc00, acc11 = acc00; \
    _Pragma("unroll")                                                             \
    for (int k = 0; k < 16; ++k) {                                                \
      if (k <= 13)      { asm volatile("s_waitcnt vmcnt(4)" ::: "memory"); }      \
      else if (k == 14) { asm volatile("s_waitcnt vmcnt(2)" ::: "memory"); }      \
      else              { asm volatile("s_waitcnt vmcnt(0)" ::: "memory"); }      \
      __builtin_amdgcn_sched_barrier(0);                                          \
      short8 b0 = *(const short8*)(smem + ring + ((2 * k) % 6) * 1024 + lane * 16);     \
      short8 b1 = *(const short8*)(smem + ring + ((2 * k + 1) % 6) * 1024 + lane * 16); \
      short8 a0 = pA0[k * 64];                                                    \
      short8 a1 = pA1[k * 64];                                                    \
      acc00 = MFMA16(a0, b0, acc00); acc01 = MFMA16(a1, b0, acc01);               \
      acc10 = MFMA16(a0, b1, acc10); acc11 = MFMA16(a1, b1, acc11);               \
      if (k <= 12) {                                                              \
        GDMA(B_IT(2 * k + 6), lds3 + ring + ((2 * k + 6) % 6) * 1024);            \
        GDMA(B_IT(2 * k + 7), lds3 + ring + ((2 * k + 7) % 6) * 1024);            \
      }                                                                           \
    }                                                                             \
    EPILOG(CBUF, HOUTP, OUTP, BSEL)                                               \
  }

__global__ __launch_bounds__(NTHR, 2) void lstm_persist(
    const unsigned short* __restrict__ Wfp, const unsigned short* __restrict__ Wh0p,
    const unsigned short* __restrict__ Wi1p, const unsigned short* __restrict__ Wh1p,
    const float* __restrict__ bA0, const float* __restrict__ bAf,
    const float* __restrict__ bB,
    unsigned short* hX,      // [8][2][65536] per-XCD replicas
    unsigned short* hG,      // [2][65536] coherent staging
    const unsigned short* zbuf,
    float* c0f, float* c1f, float* __restrict__ out, int T, unsigned* ctl) {
  extern __shared__ __align__(16) char smem[];
  auto* lds3 = (__attribute__((address_space(3))) char*)smem;
  float* red = (float*)smem;                    // aliases ring region [0,16K)
  const int wg = blockIdx.x, tid = threadIdx.x;
  const int w = tid >> 6, lane = tid & 63;
  const int p = w >> 2, s = w & 3;
  const int ring = w * 6144;                    // 6 slots x 1KB per wave
  const int res = LDS_RES + w * 12288;          // 12 resident chunks per wave
  const int xcc = (int)(__builtin_amdgcn_s_getreg((20) | (0 << 6) | (31 << 11)) & 7);
  const unsigned short* M0 = p ? Wh0p : Wfp;
  const unsigned short* M1 = p ? Wh1p : Wi1p;
  const char* WAt0 = (const char*)M0 + (((size_t)(wg * 2 + 0) * 64) + s * 16) * 1024 + lane * 16;
  const char* WAt1 = (const char*)M0 + (((size_t)(wg * 2 + 1) * 64) + s * 16) * 1024 + lane * 16;
  const char* WBt0 = (const char*)M1 + (((size_t)(wg * 2 + 0) * 64) + s * 16) * 1024 + lane * 16;
  const char* WBt1 = (const char*)M1 + (((size_t)(wg * 2 + 1) * 64) + s * 16) * 1024 + lane * 16;

  // physical-XCD role election
  if (tid == 0) *(int*)red = (int)AT_ADD(&ctl[576 + xcc * 32], 1u);

  // resident prologue: phase-A tile0 chunks k=0..11 -> LDS, once
#pragma unroll
  for (int c = 0; c < 12; ++c) GDMA(WAt0 + (size_t)c * 1024, lds3 + res + c * 1024);
  asm volatile("s_waitcnt vmcnt(0)" ::: "memory");
  __syncthreads();
  const int role = *(int*)red;
  unsigned short* Xh0 = hX + (size_t)xcc * 131072;
  unsigned short* Xh1 = Xh0 + 65536;

  // gbar #1 (counters only): all elections done
  __syncthreads();
  if (tid == 0) {
    const int g = blockIdx.x >> 5;
    unsigned a = AT_ADD(&ctl[g * 32], 1u);
    if (a == 31u) {
      unsigned m = AT_ADD(&ctl[256], 1u);
      if (m == 7u) AT_ST(&ctl[288], 1u);
    }
    while (AT_LD(&ctl[288]) < 1u) __builtin_amdgcn_s_sleep(1);
    *(int*)red = (int)AT_LD(&ctl[576 + xcc * 32]);
  }
  __syncthreads();
  const int n_x = *(int*)red;
  const int n_c = n_x < 16 ? n_x : 16;
  __syncthreads();

  int bno = 2, lbno = 1;
  for (int t = 0; t < T; ++t) {
    {  // phase A: gates0 = Wfused*h1(t-1) + Whh0*h0(t-1) -> h0(t), c0
      const unsigned short* Asrc = (p == 0) ? ((t == 0) ? zbuf : Xh1) : Xh0;
      const float* bsel = (t == 0) ? bA0 : bAf;
      PHASE_A(c0f, hG, (float*)nullptr, bsel)
    }
    phase_sync(ctl, bno++, lbno++, xcc, role, n_x, n_c, w, lane, hG, Xh0);
    {  // phase B: gates1 = Wih1*h0(t) + Whh1*h1(t-1) -> h1(t), c1, out(t)
      const unsigned short* Asrc = (p == 0) ? Xh0 : Xh1;
      PHASE_B(c1f, hG + 65536, out + (size_t)t * BH, bB)
    }
    phase_sync(ctl, bno++, lbno++, xcc, role, n_x, n_c, w, lane, hG + 65536, Xh1);
  }
}

extern "C" void kernel_launch(void* const* d_in, const int* in_sizes, int n_in,
                              void* d_out, int out_size, void* d_ws, size_t ws_size,
                              hipStream_t stream) {
  const float* h0 = (const float*)d_in[0];
  const float* c0 = (const float*)d_in[1];
  const float* Wih = (const float*)d_in[2];
  const float* Whh = (const float*)d_in[3];
  const float* bih = (const float*)d_in[4];
  const float* bhh = (const float*)d_in[5];
  const float* Wout = (const float*)d_in[6];
  const float* bout = (const float*)d_in[7];
  float* out = (float*)d_out;
  const int T = out_size / BH;

  unsigned short* Wfp = (unsigned short*)d_ws;
  unsigned short* Wh0p = Wfp + WMAT;
  unsigned short* Wi1p = Wfp + 2 * WMAT;
  unsigned short* Wh1p = Wfp + 3 * WMAT;
  unsigned short* tmpA = Wi1p;    // alias, dead after gemm_pack_k
  unsigned short* WoutT = Wh1p;   // alias, dead after gemm_pack_k
  unsigned short* S = Wfp + 4 * WMAT;
  unsigned short* hX = S;                    // 8*2*65536 = 1,048,576
  unsigned short* hG = S + 1048576;          // 2*65536
  unsigned short* zbuf = S + 1179648;        // 65536
  float* F = (float*)(S + 1245184);
  float* c0f = F;
  float* c1f = F + 65536;
  float* bA0 = F + 131072;
  float* bAf = F + 139264;
  float* bB = F + 147456;
  unsigned* ctl = (unsigned*)(F + 155648);   // 832 u32

  cvt_bf16_k<<<2048, 256, 0, stream>>>(Wih, tmpA, (long)(WMAT / 4));
  tcvt_k<<<dim3(32, 32), 256, 0, stream>>>(Wout, WoutT);
  gemm_pack_k<<<dim3(64, 16), 256, 0, stream>>>(tmpA, WoutT, Wfp);
  pack_W1_k<<<512, 256, 0, stream>>>(Whh, Wh0p);
  pack_W1_k<<<512, 256, 0, stream>>>(Wih + WMAT, Wi1p);
  pack_W1_k<<<512, 256, 0, stream>>>(Whh + WMAT, Wh1p);
  bias_k<<<1024, 512, 0, stream>>>(Wih, bout, bih, bhh, bA0, bAf, bB);
  init_k<<<256, 256, 0, stream>>>(h0, c0, hX, zbuf, c0f, c1f, ctl);

  (void)hipFuncSetAttribute((const void*)lstm_persist,
                            hipFuncAttributeMaxDynamicSharedMemorySize, LDS_BYTES);
  lstm_persist<<<NWG, NTHR, LDS_BYTES, stream>>>(Wfp, Wh0p, Wi1p, Wh1p,
                                                 bA0, bAf, bB,
                                                 hX, hG, zbuf, c0f, c1f, out, T, ctl);
}

// Round 11
// 3735.818 us; speedup vs baseline: 1.2821x; 1.0041x over previous
//
#include <hip/hip_runtime.h>

// ---------------------------------------------------------------------------
// dLSTM R11 = R10 + continuous weight streaming across phase boundaries.
// R10 analysis: weights have zero reuse -> stream pinned at per-CU MSHR wall
// (~12-15 B/cy/CU); per phase ~4us of sync/epilogue time idles the memory
// system. R11: (1) LDS = full 160KB, red[] gets own 16KB (rings survive the
// epilogue); (2) next phase's 6 W-ring prefetches issued right after the
// epilogue stores (W addresses t-invariant; A NOT prefetched - needs copier);
// (3) phase_sync drains with vmcnt(6): h-stores are older than the 6 newest
// prefetches -> visibility guaranteed, stream keeps flying through barrier.
// sched_barrier(0) prevents reordering prologue GDMAs before the stores.
// ---------------------------------------------------------------------------

typedef __attribute__((ext_vector_type(8))) short short8;
typedef __attribute__((ext_vector_type(4))) short short4v;
typedef __attribute__((ext_vector_type(4))) float f32x4;
typedef __attribute__((ext_vector_type(4))) unsigned int u32x4;

#define MFMA16(a, b, c) __builtin_amdgcn_mfma_f32_16x16x32_bf16((a), (b), (c), 0, 0, 0)
#define GDMA(gp, lp)                                                        \
  __builtin_amdgcn_global_load_lds(                                         \
      (const __attribute__((address_space(1))) unsigned int*)(gp),          \
      (__attribute__((address_space(3))) unsigned int*)(lp), 16, 0, 0)

static constexpr int BATCH = 32;
static constexpr int HID = 2048;
static constexpr int NWG = 256;
static constexpr int NTHR = 512;           // 8 waves
static constexpr int BH = BATCH * HID;     // 65536
static constexpr size_t WMAT = (size_t)8192 * 2048;
// LDS: [0,48K) rings 6KB/wave | [48K,144K) resident 12KB/wave | [144K,160K) red
static constexpr int LDS_RES = 49152;
static constexpr int LDS_RED = 147456;
static constexpr int LDS_BYTES = 163840;   // full 160 KB

#define AT_ADD(p, v) __hip_atomic_fetch_add((p), (v), __ATOMIC_RELAXED, __HIP_MEMORY_SCOPE_AGENT)
#define AT_LD(p) __hip_atomic_load((p), __ATOMIC_RELAXED, __HIP_MEMORY_SCOPE_AGENT)
#define AT_ST(p, v) __hip_atomic_store((p), (v), __ATOMIC_RELAXED, __HIP_MEMORY_SCOPE_AGENT)

__device__ __forceinline__ unsigned short f2bf(float x) {
  unsigned u = __float_as_uint(x);
  u += 0x7FFFu + ((u >> 16) & 1u);
  return (unsigned short)(u >> 16);
}
__device__ __forceinline__ float sigm(float x) { return 1.f / (1.f + __expf(-x)); }
__device__ __forceinline__ float tanh_(float x) {
  float e = __expf(2.f * x);
  return 1.f - 2.f / (e + 1.f);
}

__global__ void cvt_bf16_k(const float* __restrict__ s, unsigned short* __restrict__ d,
                           long n4) {
  long i = blockIdx.x * (long)blockDim.x + threadIdx.x;
  long st = (long)gridDim.x * blockDim.x;
  for (; i < n4; i += st) {
    float4 v = ((const float4*)s)[i];
    short4v o;
    o.x = (short)f2bf(v.x); o.y = (short)f2bf(v.y);
    o.z = (short)f2bf(v.z); o.w = (short)f2bf(v.w);
    ((short4v*)d)[i] = o;
  }
}

// Wout f32 [2048][2048] -> WoutT bf16 transposed
__global__ void tcvt_k(const float* __restrict__ src, unsigned short* __restrict__ dst) {
  __shared__ float T[64][65];
  const int jb = blockIdx.x * 64, kb = blockIdx.y * 64;
  const int tid = threadIdx.x;
#pragma unroll
  for (int r = 0; r < 4; ++r) {
    const int row = r * 16 + (tid >> 4), c4 = (tid & 15) * 4;
    float4 v = *(const float4*)&src[(size_t)(jb + row) * 2048 + kb + c4];
    T[row][c4] = v.x; T[row][c4 + 1] = v.y; T[row][c4 + 2] = v.z; T[row][c4 + 3] = v.w;
  }
  __syncthreads();
#pragma unroll
  for (int r = 0; r < 4; ++r) {
    const int k = r * 16 + (tid >> 4), j4 = (tid & 15) * 4;
    short4v o;
    o.x = (short)f2bf(T[j4][k]);     o.y = (short)f2bf(T[j4 + 1][k]);
    o.z = (short)f2bf(T[j4 + 2][k]); o.w = (short)f2bf(T[j4 + 3][k]);
    *(short4v*)&dst[(size_t)(kb + k) * 2048 + jb + j4] = o;
  }
}

// Wfp(packed) = A[8192x2048] . Bt[2048x2048]^T ; grid(64,16), 4 waves (2x2)
__global__ void gemm_pack_k(const unsigned short* __restrict__ A,
                            const unsigned short* __restrict__ Bt,
                            unsigned short* __restrict__ Wfp) {
  __shared__ __align__(16) unsigned short As[128][72], Bs[128][72];
  const int tid = threadIdx.x, wv = tid >> 6, lane = tid & 63;
  const int wm = wv >> 1, wn = wv & 1;
  const int g0 = blockIdx.x * 128, k0 = blockIdx.y * 128;
  f32x4 acc[4][4];
#pragma unroll
  for (int i = 0; i < 4; ++i)
#pragma unroll
    for (int j = 0; j < 4; ++j) acc[i][j] = (f32x4){0.f, 0.f, 0.f, 0.f};

  for (int kt = 0; kt < 32; ++kt) {
#pragma unroll
    for (int rr = 0; rr < 4; ++rr) {
      const int row = rr * 32 + (tid >> 3), c8 = (tid & 7) * 8;
      *(short8*)&As[row][c8] = *(const short8*)&A[(size_t)(g0 + row) * 2048 + kt * 64 + c8];
      *(short8*)&Bs[row][c8] = *(const short8*)&Bt[(size_t)(k0 + row) * 2048 + kt * 64 + c8];
    }
    __syncthreads();
#pragma unroll
    for (int kk = 0; kk < 2; ++kk) {
      short8 af[4], bf[4];
#pragma unroll
      for (int mi = 0; mi < 4; ++mi)
        af[mi] = *(const short8*)&As[wm * 64 + mi * 16 + (lane & 15)][kk * 32 + (lane >> 4) * 8];
#pragma unroll
      for (int ni = 0; ni < 4; ++ni)
        bf[ni] = *(const short8*)&Bs[wn * 64 + ni * 16 + (lane & 15)][kk * 32 + (lane >> 4) * 8];
#pragma unroll
      for (int mi = 0; mi < 4; ++mi)
#pragma unroll
        for (int ni = 0; ni < 4; ++ni)
          acc[mi][ni] = MFMA16(af[mi], bf[ni], acc[mi][ni]);
    }
    __syncthreads();
  }
#pragma unroll
  for (int mi = 0; mi < 4; ++mi)
#pragma unroll
    for (int ni = 0; ni < 4; ++ni)
#pragma unroll
      for (int r = 0; r < 4; ++r) {
        const int g = g0 + wm * 64 + mi * 16 + (lane >> 4) * 4 + r;
        const int k = k0 + wn * 64 + ni * 16 + (lane & 15);
        const int gateblk = g >> 11, gcol = g & 2047;
        const int wgp = gcol >> 3, nn = (gcol & 7) + 8 * (gateblk & 1), tile = gateblk >> 1;
        const int kblk = k >> 5, e = k & 7, lane_p = nn + 16 * ((k >> 3) & 3);
        Wfp[(((size_t)(wgp * 2 + tile) * 64 + kblk) * 64 + lane_p) * 8 + e] =
            f2bf(acc[mi][ni][r]);
      }
}

__global__ void pack_W1_k(const float* __restrict__ src, unsigned short* __restrict__ dst) {
  const int bid = blockIdx.x;              // 512: [wg(256)][tile(2)]
  const int wg = bid >> 1, tile = bid & 1;
  const int tid = threadIdx.x;
  __shared__ __align__(16) unsigned short L[16][2056];
  for (int i = tid; i < 16 * 512; i += 256) {
    const int r = i >> 9, c4 = i & 511;
    const int gr = tile * 4096 + (r < 8 ? wg * 8 + r : 2048 + wg * 8 + r - 8);
    float4 v = ((const float4*)(src + (size_t)gr * 2048))[c4];
    short4v o;
    o.x = (short)f2bf(v.x); o.y = (short)f2bf(v.y);
    o.z = (short)f2bf(v.z); o.w = (short)f2bf(v.w);
    *(short4v*)&L[r][c4 * 4] = o;
  }
  __syncthreads();
  short8* dchunks = (short8*)dst;
  const size_t cbase = (size_t)(wg * 2 + tile) * 64;
  for (int c = tid; c < 4096; c += 256) {
    const int lane = c & 63, kblk = c >> 6;
    const int nn = lane & 15, kb = (lane >> 4) << 3;
    short8 v = *(const short8*)&L[nn][kblk * 32 + kb];
    dchunks[(cbase + kblk) * 64 + lane] = v;
  }
}

__global__ void bias_k(const float* __restrict__ Wih, const float* __restrict__ bout,
                       const float* __restrict__ bih, const float* __restrict__ bhh,
                       float* bA0, float* bAf, float* bB) {
  const int g = blockIdx.x * 8 + (threadIdx.x >> 6);
  const int lane = threadIdx.x & 63;
  float s = 0.f;
  for (int i = 0; i < 32; ++i)
    s += Wih[(size_t)g * 2048 + i * 64 + lane] * bout[i * 64 + lane];
  for (int off = 32; off; off >>= 1) s += __shfl_down(s, off);
  if (lane == 0) {
    const float b0 = bih[g] + bhh[g];
    bA0[g] = b0; bAf[g] = b0 + s;
    bB[g] = bih[8192 + g] + bhh[8192 + g];
  }
}

// init: Xh[8 xcds][2 matrices] = initial h (packed layout); zbuf; c; ctl
__global__ void init_k(const float* __restrict__ h0, const float* __restrict__ c0,
                       unsigned short* hX, unsigned short* zbuf,
                       float* c0f, float* c1f, unsigned* ctl) {
  int i = blockIdx.x * blockDim.x + threadIdx.x;
  if (i < BH) {
    const int e = i & 7, lane = (i >> 3) & 63, kblk = (i >> 9) & 63, mtile = i >> 15;
    const int m = mtile * 16 + (lane & 15);
    const int k = kblk * 32 + ((lane >> 4) << 3) + e;
    const unsigned short v0 = f2bf(h0[m * HID + k]);
    const unsigned short v1 = f2bf(h0[BH + m * HID + k]);
#pragma unroll
    for (int x = 0; x < 8; ++x) {
      hX[(size_t)x * 131072 + i] = v0;
      hX[(size_t)x * 131072 + 65536 + i] = v1;
    }
    zbuf[i] = 0;
    c0f[i] = c0[i];
    c1f[i] = c0[BH + i];
  }
  if (i < 832) ctl[i] = 0u;
}

// ---------------- phase sync: counter gbar -> copy hG->Xh[xcd] -> lbar ------
// Entry waits vmcnt(6): the 6 newest VMEM ops are the next-phase W-prefetches;
// everything older (h/out/c stores) is guaranteed complete. Prefetches keep
// streaming through the barrier + copy window.
__device__ __forceinline__ void phase_sync(unsigned* ctl, int bno, int lbno, int xcc,
                                           int role, int n_x, int n_c, int w, int lane,
                                           const unsigned short* hGm,
                                           unsigned short* Xm) {
  asm volatile("s_waitcnt vmcnt(6)" ::: "memory");   // stores drained, prefetch alive
  __syncthreads();
  if (threadIdx.x == 0) {
    const int g = blockIdx.x >> 5;
    unsigned a = AT_ADD(&ctl[g * 32], 1u);
    if (a == (unsigned)(32 * bno - 1)) {
      unsigned m = AT_ADD(&ctl[256], 1u);
      if (m == (unsigned)(8 * bno - 1)) AT_ST(&ctl[288], (unsigned)bno);
    }
    while (AT_LD(&ctl[288]) < (unsigned)bno) __builtin_amdgcn_s_sleep(1);
  }
  __syncthreads();
  // copiers: hG (sc0sc1 loads: coherence point) -> Xh[xcd] (plain stores ->
  // dirty in OWN XCD's L2; physical co-location by XCC_ID election)
  if (role < n_c) {
    for (int c = role * 8 + w; c < 128; c += n_c * 8) {
      const unsigned short* sp = hGm + c * 512 + lane * 8;
      u32x4 v;
      asm volatile("global_load_dwordx4 %0, %1, off sc0 sc1"
                   : "=v"(v) : "v"((unsigned long long)(size_t)sp) : "memory");
      asm volatile("s_waitcnt vmcnt(0)" ::: "memory");
      *(u32x4*)(Xm + c * 512 + lane * 8) = v;
    }
    asm volatile("s_waitcnt vmcnt(0)" ::: "memory");
  }
  __syncthreads();
  if (threadIdx.x == 0) {
    AT_ADD(&ctl[320 + xcc * 32], 1u);
    while (AT_LD(&ctl[320 + xcc * 32]) < (unsigned)(n_x * lbno))
      __builtin_amdgcn_s_sleep(1);
  }
  __syncthreads();
  asm volatile("buffer_inv" ::: "memory");   // L1-only: fresh view of Xh
}

// shared epilogue: red[] (own 16KB, no ring alias) -> gates -> cell
// h published via sc0sc1 store to hG staging (device-coherent, tiny).
#define EPILOG(CBUF, HOUTP, OUTP, BSEL)                                           \
  __syncthreads();                                                                \
  *(f32x4*)&red[((w * 2 + 0) * 64 + lane) * 4] = acc00;                           \
  *(f32x4*)&red[((w * 2 + 1) * 64 + lane) * 4] = acc01;                           \
  __syncthreads();                                                                \
  float gi = 0.f, gf_ = 0.f;                                                      \
  if (tid < 256) {                                                                \
    const int b = tid >> 3, cc = tid & 7, m = b >> 4, br = b & 15;                \
    const int reg = br & 3, lb = (br >> 2) << 4;                                  \
    _Pragma("unroll")                                                             \
    for (int ww = 0; ww < 8; ++ww) {                                              \
      gi  += red[((ww * 2 + m) * 64 + lb + cc) * 4 + reg];                        \
      gf_ += red[((ww * 2 + m) * 64 + lb + cc + 8) * 4 + reg];                    \
    }                                                                             \
  }                                                                               \
  __syncthreads();                                                                \
  *(f32x4*)&red[((w * 2 + 0) * 64 + lane) * 4] = acc10;                           \
  *(f32x4*)&red[((w * 2 + 1) * 64 + lane) * 4] = acc11;                           \
  __syncthreads();                                                                \
  if (tid < 256) {                                                                \
    const int b = tid >> 3, cc = tid & 7, m = b >> 4, br = b & 15;                \
    const int reg = br & 3, lb = (br >> 2) << 4;                                  \
    float gg = 0.f, go = 0.f;                                                     \
    _Pragma("unroll")                                                             \
    for (int ww = 0; ww < 8; ++ww) {                                              \
      gg += red[((ww * 2 + m) * 64 + lb + cc) * 4 + reg];                         \
      go += red[((ww * 2 + m) * 64 + lb + cc + 8) * 4 + reg];                     \
    }                                                                             \
    const int col = wg * 8 + cc;                                                  \
    gi  += (BSEL)[col];                                                           \
    gf_ += (BSEL)[2048 + col];                                                    \
    gg  += (BSEL)[4096 + col];                                                    \
    go  += (BSEL)[6144 + col];                                                    \
    const float iv = sigm(gi), fv = sigm(gf_), gv = tanh_(gg), ov = sigm(go);     \
    const float cold = (CBUF)[b * HID + col];                                     \
    const float cnew = fv * cold + iv * gv;                                       \
    const float hnew = ov * tanh_(cnew);                                          \
    (CBUF)[b * HID + col] = cnew;                                                 \
    const int kblk = col >> 5, lh = (col >> 3) & 3, e = col & 7;                  \
    const int lane_p = (b & 15) | (lh << 4), mt = b >> 4;                         \
    const unsigned hv = (unsigned)f2bf(hnew);                                     \
    unsigned long long ha = (unsigned long long)(size_t)                          \
        ((HOUTP) + ((size_t)(mt * 64 + kblk) * 64 + lane_p) * 8 + e);             \
    asm volatile("global_store_short %0, %1, off sc0 sc1"                         \
                 :: "v"(ha), "v"(hv) : "memory");                                 \
    if (OUTP) ((float*)(OUTP))[b * HID + col] = hnew;                             \
  }

// W-stream item maps (t-invariant -> safe to prefetch across barriers)
#define A_IT(i)                                                                   \
  ((i) < 12 ? (WAt1 + (size_t)(i) * 1024)                                         \
            : ((((i) - 12) & 1) ? (WAt1 + (size_t)(12 + (((i) - 12) >> 1)) * 1024)\
                                : (WAt0 + (size_t)(12 + (((i) - 12) >> 1)) * 1024)))
#define B_IT(i)                                                                   \
  (((i) & 1) ? (WBt1 + (size_t)((i) >> 1) * 1024) : (WBt0 + (size_t)((i) >> 1) * 1024))

#define PROLOG_A                                                                  \
  __builtin_amdgcn_sched_barrier(0);                                              \
  { _Pragma("unroll")                                                             \
    for (int i = 0; i < 6; ++i) GDMA(A_IT(i), lds3 + ring + (i % 6) * 1024); }    \
  __builtin_amdgcn_sched_barrier(0);
#define PROLOG_B                                                                  \
  __builtin_amdgcn_sched_barrier(0);                                              \
  { _Pragma("unroll")                                                             \
    for (int i = 0; i < 6; ++i) GDMA(B_IT(i), lds3 + ring + (i % 6) * 1024); }    \
  __builtin_amdgcn_sched_barrier(0);

// Phase A (prologue already in flight): resident tile0 k<12 from LDS; stream
// 20 items. wait vmcnt: k<12:5, k=12,13:4, k=14:2, k=15:0. issue: k<=11 ->
// item k+6; k==12 -> items 18,19.
#define PHASE_A(CBUF, HOUTP, OUTP, BSEL)                                          \
  {                                                                               \
    const short8* pA0 = (const short8*)Asrc + (s * 16) * 64 + lane;               \
    const short8* pA1 = pA0 + 64 * 64;                                            \
    f32x4 acc00 = {0.f, 0.f, 0.f, 0.f}, acc01 = acc00, acc10 = acc00, acc11 = acc00; \
    _Pragma("unroll")                                                             \
    for (int k = 0; k < 16; ++k) {                                                \
      if (k < 12)       { asm volatile("s_waitcnt vmcnt(5)" ::: "memory"); }      \
      else if (k <= 13) { asm volatile("s_waitcnt vmcnt(4)" ::: "memory"); }      \
      else if (k == 14) { asm volatile("s_waitcnt vmcnt(2)" ::: "memory"); }      \
      else              { asm volatile("s_waitcnt vmcnt(0)" ::: "memory"); }      \
      __builtin_amdgcn_sched_barrier(0);                                          \
      short8 b0 = (k < 12)                                                        \
          ? *(const short8*)(smem + res + k * 1024 + lane * 16)                   \
          : *(const short8*)(smem + ring + ((12 + 2 * (k - 12)) % 6) * 1024 + lane * 16); \
      short8 b1 = (k < 12)                                                        \
          ? *(const short8*)(smem + ring + (k % 6) * 1024 + lane * 16)            \
          : *(const short8*)(smem + ring + ((13 + 2 * (k - 12)) % 6) * 1024 + lane * 16); \
      short8 a0 = pA0[k * 64];                                                    \
      short8 a1 = pA1[k * 64];                                                    \
      acc00 = MFMA16(a0, b0, acc00); acc01 = MFMA16(a1, b0, acc01);               \
      acc10 = MFMA16(a0, b1, acc10); acc11 = MFMA16(a1, b1, acc11);               \
      if (k <= 11) { GDMA(A_IT(k + 6), lds3 + ring + ((k + 6) % 6) * 1024); }     \
      if (k == 12) {                                                              \
        GDMA(A_IT(18), lds3 + ring + 0 * 1024);                                   \
        GDMA(A_IT(19), lds3 + ring + 1 * 1024);                                   \
      }                                                                           \
    }                                                                             \
    EPILOG(CBUF, HOUTP, OUTP, BSEL)                                               \
  }

// Phase B: 32 items, pairs per k. wait: k<=13:4, k=14:2, k=15:0; issue 2
// items (2k+6,2k+7) for k<=12.
#define PHASE_B(CBUF, HOUTP, OUTP, BSEL)                                          \
  {                                                                               \
    const short8* pA0 = (const short8*)Asrc + (s * 16) * 64 + lane;               \
    const short8* pA1 = pA0 + 64 * 64;                                            \
    f32x4 acc00 = {0.f, 0.f, 0.f, 0.f}, acc01 = acc00, acc10 = acc00, acc11 = acc00; \
    _Pragma("unroll")                                                             \
    for (int k = 0; k < 16; ++k) {                                                \
      if (k <= 13)      { asm volatile("s_waitcnt vmcnt(4)" ::: "memory"); }      \
      else if (k == 14) { asm volatile("s_waitcnt vmcnt(2)" ::: "memory"); }      \
      else              { asm volatile("s_waitcnt vmcnt(0)" ::: "memory"); }      \
      __builtin_amdgcn_sched_barrier(0);                                          \
      short8 b0 = *(const short8*)(smem + ring + ((2 * k) % 6) * 1024 + lane * 16);     \
      short8 b1 = *(const short8*)(smem + ring + ((2 * k + 1) % 6) * 1024 + lane * 16); \
      short8 a0 = pA0[k * 64];                                                    \
      short8 a1 = pA1[k * 64];                                                    \
      acc00 = MFMA16(a0, b0, acc00); acc01 = MFMA16(a1, b0, acc01);               \
      acc10 = MFMA16(a0, b1, acc10); acc11 = MFMA16(a1, b1, acc11);               \
      if (k <= 12) {                                                              \
        GDMA(B_IT(2 * k + 6), lds3 + ring + ((2 * k + 6) % 6) * 1024);            \
        GDMA(B_IT(2 * k + 7), lds3 + ring + ((2 * k + 7) % 6) * 1024);            \
      }                                                                           \
    }                                                                             \
    EPILOG(CBUF, HOUTP, OUTP, BSEL)                                               \
  }

__global__ __launch_bounds__(NTHR, 2) void lstm_persist(
    const unsigned short* __restrict__ Wfp, const unsigned short* __restrict__ Wh0p,
    const unsigned short* __restrict__ Wi1p, const unsigned short* __restrict__ Wh1p,
    const float* __restrict__ bA0, const float* __restrict__ bAf,
    const float* __restrict__ bB,
    unsigned short* hX,      // [8][2][65536] per-XCD replicas
    unsigned short* hG,      // [2][65536] coherent staging
    const unsigned short* zbuf,
    float* c0f, float* c1f, float* __restrict__ out, int T, unsigned* ctl) {
  extern __shared__ __align__(16) char smem[];
  auto* lds3 = (__attribute__((address_space(3))) char*)smem;
  float* red = (float*)(smem + LDS_RED);        // own 16KB, no ring alias
  const int wg = blockIdx.x, tid = threadIdx.x;
  const int w = tid >> 6, lane = tid & 63;
  const int p = w >> 2, s = w & 3;
  const int ring = w * 6144;                    // 6 slots x 1KB per wave
  const int res = LDS_RES + w * 12288;          // 12 resident chunks per wave
  const int xcc = (int)(__builtin_amdgcn_s_getreg((20) | (0 << 6) | (31 << 11)) & 7);
  const unsigned short* M0 = p ? Wh0p : Wfp;
  const unsigned short* M1 = p ? Wh1p : Wi1p;
  const char* WAt0 = (const char*)M0 + (((size_t)(wg * 2 + 0) * 64) + s * 16) * 1024 + lane * 16;
  const char* WAt1 = (const char*)M0 + (((size_t)(wg * 2 + 1) * 64) + s * 16) * 1024 + lane * 16;
  const char* WBt0 = (const char*)M1 + (((size_t)(wg * 2 + 0) * 64) + s * 16) * 1024 + lane * 16;
  const char* WBt1 = (const char*)M1 + (((size_t)(wg * 2 + 1) * 64) + s * 16) * 1024 + lane * 16;

  // physical-XCD role election
  if (tid == 0) *(int*)red = (int)AT_ADD(&ctl[576 + xcc * 32], 1u);

  // resident prologue: phase-A tile0 chunks k=0..11 -> LDS, once
#pragma unroll
  for (int c = 0; c < 12; ++c) GDMA(WAt0 + (size_t)c * 1024, lds3 + res + c * 1024);
  asm volatile("s_waitcnt vmcnt(0)" ::: "memory");
  __syncthreads();
  const int role = *(int*)red;
  unsigned short* Xh0 = hX + (size_t)xcc * 131072;
  unsigned short* Xh1 = Xh0 + 65536;

  // gbar #1 (counters only): all elections done
  __syncthreads();
  if (tid == 0) {
    const int g = blockIdx.x >> 5;
    unsigned a = AT_ADD(&ctl[g * 32], 1u);
    if (a == 31u) {
      unsigned m = AT_ADD(&ctl[256], 1u);
      if (m == 7u) AT_ST(&ctl[288], 1u);
    }
    while (AT_LD(&ctl[288]) < 1u) __builtin_amdgcn_s_sleep(1);
    *(int*)red = (int)AT_LD(&ctl[576 + xcc * 32]);
  }
  __syncthreads();
  const int n_x = *(int*)red;
  const int n_c = n_x < 16 ? n_x : 16;
  __syncthreads();

  PROLOG_A   // first phase's W-prologue

  int bno = 2, lbno = 1;
  for (int t = 0; t < T; ++t) {
    {  // phase A: gates0 = Wfused*h1(t-1) + Whh0*h0(t-1) -> h0(t), c0
      const unsigned short* Asrc = (p == 0) ? ((t == 0) ? zbuf : Xh1) : Xh0;
      const float* bsel = (t == 0) ? bA0 : bAf;
      PHASE_A(c0f, hG, (float*)nullptr, bsel)
    }
    PROLOG_B   // next phase's W-prefetch: flies through the barrier
    phase_sync(ctl, bno++, lbno++, xcc, role, n_x, n_c, w, lane, hG, Xh0);
    {  // phase B: gates1 = Wih1*h0(t) + Whh1*h1(t-1) -> h1(t), c1, out(t)
      const unsigned short* Asrc = (p == 0) ? Xh0 : Xh1;
      PHASE_B(c1f, hG + 65536, out + (size_t)t * BH, bB)
    }
    PROLOG_A   // t+1 phase A prefetch (harmless surplus at t=T-1)
    phase_sync(ctl, bno++, lbno++, xcc, role, n_x, n_c, w, lane, hG + 65536, Xh1);
  }
}

extern "C" void kernel_launch(void* const* d_in, const int* in_sizes, int n_in,
                              void* d_out, int out_size, void* d_ws, size_t ws_size,
                              hipStream_t stream) {
  const float* h0 = (const float*)d_in[0];
  const float* c0 = (const float*)d_in[1];
  const float* Wih = (const float*)d_in[2];
  const float* Whh = (const float*)d_in[3];
  const float* bih = (const float*)d_in[4];
  const float* bhh = (const float*)d_in[5];
  const float* Wout = (const float*)d_in[6];
  const float* bout = (const float*)d_in[7];
  float* out = (float*)d_out;
  const int T = out_size / BH;

  unsigned short* Wfp = (unsigned short*)d_ws;
  unsigned short* Wh0p = Wfp + WMAT;
  unsigned short* Wi1p = Wfp + 2 * WMAT;
  unsigned short* Wh1p = Wfp + 3 * WMAT;
  unsigned short* tmpA = Wi1p;    // alias, dead after gemm_pack_k
  unsigned short* WoutT = Wh1p;   // alias, dead after gemm_pack_k
  unsigned short* S = Wfp + 4 * WMAT;
  unsigned short* hX = S;                    // 8*2*65536 = 1,048,576
  unsigned short* hG = S + 1048576;          // 2*65536
  unsigned short* zbuf = S + 1179648;        // 65536
  float* F = (float*)(S + 1245184);
  float* c0f = F;
  float* c1f = F + 65536;
  float* bA0 = F + 131072;
  float* bAf = F + 139264;
  float* bB = F + 147456;
  unsigned* ctl = (unsigned*)(F + 155648);   // 832 u32

  cvt_bf16_k<<<2048, 256, 0, stream>>>(Wih, tmpA, (long)(WMAT / 4));
  tcvt_k<<<dim3(32, 32), 256, 0, stream>>>(Wout, WoutT);
  gemm_pack_k<<<dim3(64, 16), 256, 0, stream>>>(tmpA, WoutT, Wfp);
  pack_W1_k<<<512, 256, 0, stream>>>(Whh, Wh0p);
  pack_W1_k<<<512, 256, 0, stream>>>(Wih + WMAT, Wi1p);
  pack_W1_k<<<512, 256, 0, stream>>>(Whh + WMAT, Wh1p);
  bias_k<<<1024, 512, 0, stream>>>(Wih, bout, bih, bhh, bA0, bAf, bB);
  init_k<<<256, 256, 0, stream>>>(h0, c0, hX, zbuf, c0f, c1f, ctl);

  (void)hipFuncSetAttribute((const void*)lstm_persist,
                            hipFuncAttributeMaxDynamicSharedMemorySize, LDS_BYTES);
  lstm_persist<<<NWG, NTHR, LDS_BYTES, stream>>>(Wfp, Wh0p, Wi1p, Wh1p,
                                                 bA0, bAf, bB,
                                                 hX, hG, zbuf, c0f, c1f, out, T, ctl);
}